// Round 2
// baseline (526.400 us; speedup 1.0000x reference)
//
#include <hip/hip_runtime.h>
#include <hip/hip_fp16.h>

// SMINSparseMeanPool: x (B,D,N=64) f32 -> out (B,D,C=4,N,N) f32
// out[b,d,c,s,e] = mask(s,e) * (P[EE]-P[SS]) / (EE-SS), P = zero-prefixed cumsum of x[b,d,:]
//
// Strategy: the (c,s,e) -> (SS, EE, mask, 1/count) mapping is static (16384 entries).
// Kernel 1 builds a packed u32 table in d_ws:  ss | ee<<8 | f16(1/count)<<16
// (masked entries = 0, which self-zeroes since (P[0]-P[0])*0 == 0).
// Kernel 2 is then a near-pure write stream: per output = decode + 2 LDS reads + sub + cvt + mul.

#define NN 64
#define COUT 4
#define TAB_N (COUT * NN * NN)   // 16384 entries = 64 KB

__global__ __launch_bounds__(256)
void smin_build_table(unsigned int* __restrict__ tab) {
    const int idx = blockIdx.x * 256 + threadIdx.x;   // c*4096 + s*64 + e
    const int c = idx >> 12;
    const int s = (idx >> 6) & 63;
    const int e = idx & 63;
    const int d = e - s;
    bool m;
    if (d < 0)        m = false;
    else if (d <= 15) m = true;                        // stride-1 band (incl diagonal)
    else if (d <= 31) m = (d & 1) && !(s & 1);         // stride-2: odd offsets 17..31, s even
    else              m = ((d & 3) == 3) && !(s & 3);  // stride-4: offsets 35..63 step 4, s%4==0

    unsigned int packed = 0u;
    if (m) {
        const int L = d + 1;
        int ss, ee;
        if (L < COUT) { ss = s; ee = e + 1; }
        else {
            ss = s + ((c * L) >> 2);
            ee = s + (((c + 1) * L) >> 2);
        }
        if (ee < ss + 1) ee = ss + 1;
        const float rcp = 1.0f / (float)(ee - ss);     // one-time cost, IEEE div fine
        const unsigned short h = __half_as_ushort(__float2half(rcp));
        packed = (unsigned)ss | ((unsigned)ee << 8) | ((unsigned)h << 16);
    }
    tab[idx] = packed;
}

__global__ __launch_bounds__(256)
void smin_pool_kernel(const float* __restrict__ x,
                      const uint4* __restrict__ tab4,
                      float* __restrict__ out) {
    __shared__ float P[NN + 1];
    const int bd = blockIdx.x;
    const int t  = threadIdx.x;

    // wave-0: load 64 inputs, inclusive shuffle-scan, prefix into LDS
    if (t < 64) {
        float v = x[(size_t)bd * NN + t];
        #pragma unroll
        for (int off = 1; off < 64; off <<= 1) {
            float u = __shfl_up(v, off, 64);
            if (t >= off) v += u;
        }
        P[t + 1] = v;
        if (t == 0) P[0] = 0.0f;
    }
    __syncthreads();

    float4* out4 = (float4*)(out + (size_t)bd * TAB_N);

    #pragma unroll
    for (int k = 0; k < 16; ++k) {
        const int idx4 = t + k * 256;          // [0, 4096)
        const uint4 tv = tab4[idx4];           // 4 packed entries (L2-resident table)
        float4 r;
        {
            const unsigned v = tv.x;
            r.x = (P[(v >> 8) & 255] - P[v & 255]) *
                  __half2float(__ushort_as_half((unsigned short)(v >> 16)));
        }
        {
            const unsigned v = tv.y;
            r.y = (P[(v >> 8) & 255] - P[v & 255]) *
                  __half2float(__ushort_as_half((unsigned short)(v >> 16)));
        }
        {
            const unsigned v = tv.z;
            r.z = (P[(v >> 8) & 255] - P[v & 255]) *
                  __half2float(__ushort_as_half((unsigned short)(v >> 16)));
        }
        {
            const unsigned v = tv.w;
            r.w = (P[(v >> 8) & 255] - P[v & 255]) *
                  __half2float(__ushort_as_half((unsigned short)(v >> 16)));
        }
        out4[idx4] = r;
    }
}

extern "C" void kernel_launch(void* const* d_in, const int* in_sizes, int n_in,
                              void* d_out, int out_size, void* d_ws, size_t ws_size,
                              hipStream_t stream) {
    const float* x = (const float*)d_in[0];
    float* out = (float*)d_out;
    unsigned int* tab = (unsigned int*)d_ws;           // 64 KB of scratch
    const int BD = in_sizes[0] / NN;                   // 16*512 = 8192 rows

    smin_build_table<<<TAB_N / 256, 256, 0, stream>>>(tab);
    smin_pool_kernel<<<BD, 256, 0, stream>>>(x, (const uint4*)d_ws, out);
}